// Round 1
// baseline (104.385 us; speedup 1.0000x reference)
//
#include <hip/hip_runtime.h>
#include <hip/hip_bf16.h>

#define N_TOK 4096        // B*T = 32*128
#define EMB_D 64
#define NEG_K 512
#define LOGITS_W 513      // 1 + NEG_K

// ---------------------------------------------------------------------------
// Kernel 1: projection x = embeds @ W + b, and zero the loss accumulator.
//   embeds [N,64], W [64,64] (d_in -> e_out), b [64] -> x [N,64]
// ---------------------------------------------------------------------------
__global__ __launch_bounds__(256) void proj_kernel(
    const float* __restrict__ embeds,
    const float* __restrict__ W,
    const float* __restrict__ b,
    float* __restrict__ x,
    float* __restrict__ loss)
{
    __shared__ float Ws[EMB_D][EMB_D];   // 16 KB
    __shared__ float Es[4][EMB_D];
    const int tid = threadIdx.x;
    const int n0 = blockIdx.x * 4;

    for (int i = tid; i < EMB_D * EMB_D; i += 256)
        Ws[i >> 6][i & 63] = W[i];
    for (int i = tid; i < 4 * EMB_D; i += 256)
        Es[i >> 6][i & 63] = embeds[(size_t)n0 * EMB_D + i];
    __syncthreads();

    const int nl = tid >> 6;    // local row 0..3
    const int e  = tid & 63;    // output dim
    float acc = b[e];
    #pragma unroll
    for (int d = 0; d < EMB_D; ++d)
        acc += Es[nl][d] * Ws[d][e];
    x[(size_t)(n0 + nl) * EMB_D + e] = acc;

    if (blockIdx.x == 0 && tid == 0) loss[0] = 0.0f;
}

// ---------------------------------------------------------------------------
// Kernel 2: per-token scoring + logits write + logsumexp loss accumulation.
// One block of 512 threads per token n. Thread k handles negative k.
// ---------------------------------------------------------------------------
__global__ __launch_bounds__(512) void score_kernel(
    const float* __restrict__ x,        // [N,64]
    const int*   __restrict__ labels,   // [N]
    const int*   __restrict__ neg,      // [N,512]
    const float* __restrict__ table,    // [1e6,64]
    float* __restrict__ logits,         // [N,513]
    float* __restrict__ loss)           // [1]
{
    const int n   = blockIdx.x;
    const int tid = threadIdx.x;

    __shared__ float xs[EMB_D];
    __shared__ float red[8];
    __shared__ float posS;
    __shared__ float Ms;

    if (tid < EMB_D) xs[tid] = x[(size_t)n * EMB_D + tid];
    __syncthreads();

    const float4* xv = (const float4*)xs;

    // ---- negative score: thread tid -> negative tid ----
    const int idx = neg[(size_t)n * NEG_K + tid];
    const float4* row = (const float4*)(table + (size_t)idx * EMB_D);
    float acc = 0.0f;
    #pragma unroll
    for (int j = 0; j < 16; ++j) {
        float4 r = row[j];
        float4 v = xv[j];        // LDS broadcast (same addr all lanes)
        acc += r.x * v.x + r.y * v.y + r.z * v.z + r.w * v.w;
    }
    logits[(size_t)n * LOGITS_W + 1 + tid] = acc;

    // ---- positive score: lanes 0..15 of wave 0 ----
    if (tid < 16) {
        const int pidx = labels[n];
        const float4* prow = (const float4*)(table + (size_t)pidx * EMB_D);
        float4 r = prow[tid];
        float4 v = xv[tid];
        float p = r.x * v.x + r.y * v.y + r.z * v.z + r.w * v.w;
        #pragma unroll
        for (int o = 8; o > 0; o >>= 1) p += __shfl_xor(p, o, 16);
        if (tid == 0) {
            posS = p;
            logits[(size_t)n * LOGITS_W] = p;
        }
    }
    __syncthreads();
    const float pos = posS;

    // ---- block max over {pos, 512 negs} ----
    float m = acc;
    #pragma unroll
    for (int o = 32; o > 0; o >>= 1) m = fmaxf(m, __shfl_xor(m, o));
    const int wave = tid >> 6;
    if ((tid & 63) == 0) red[wave] = m;
    __syncthreads();
    if (tid == 0) {
        float mm = pos;
        #pragma unroll
        for (int w = 0; w < 8; ++w) mm = fmaxf(mm, red[w]);
        Ms = mm;
    }
    __syncthreads();
    const float M = Ms;

    // ---- block sum of exp ----
    float e = expf(acc - M);
    #pragma unroll
    for (int o = 32; o > 0; o >>= 1) e += __shfl_xor(e, o);
    __syncthreads();             // all reads of red (max pass) done
    if ((tid & 63) == 0) red[wave] = e;
    __syncthreads();
    if (tid == 0) {
        float s = expf(pos - M);
        #pragma unroll
        for (int w = 0; w < 8; ++w) s += red[w];
        const float lse = M + logf(s);
        atomicAdd(loss, (lse - pos) * (1.0f / (float)N_TOK));
    }
}

extern "C" void kernel_launch(void* const* d_in, const int* in_sizes, int n_in,
                              void* d_out, int out_size, void* d_ws, size_t ws_size,
                              hipStream_t stream) {
    const float* embeds = (const float*)d_in[0];   // [32,128,64]
    const int*   labels = (const int*)d_in[1];     // [4096]
    const int*   neg    = (const int*)d_in[2];     // [4096,512]
    const float* proj_w = (const float*)d_in[3];   // [64,64]
    const float* proj_b = (const float*)d_in[4];   // [64]
    const float* table  = (const float*)d_in[5];   // [1e6,64]

    float* logits = (float*)d_out;                       // [4096,513]
    float* loss   = (float*)d_out + (size_t)N_TOK * LOGITS_W;  // [1]
    float* x      = (float*)d_ws;                        // [4096,64] scratch

    proj_kernel<<<N_TOK / 4, 256, 0, stream>>>(embeds, proj_w, proj_b, x, loss);
    score_kernel<<<N_TOK, 512, 0, stream>>>(x, labels, neg, table, logits, loss);
}